// Round 2
// baseline (615.981 us; speedup 1.0000x reference)
//
#include <hip/hip_runtime.h>

// GRU (reset_after, inference) fused with dense head.
// B=1024 rows, T=512 steps, F=16 features, H=64 hidden.
// ONE WAVE PER ROW: lane j owns hidden unit j; full U column triple (192
// VGPRs) + W fragment (48 VGPRs) live in architectural VGPRs.
// x[row][t][*] is WAVE-UNIFORM -> read via scalar loads (s_load) into SGPRs:
// no VGPRs, no LDS, no VALU issue for x. The f-loop FMA uses the SGPR as
// its one scalar operand.
// h[k] broadcast via v_readlane. Zero LDS, zero barriers in the loop.
// __launch_bounds__(64,2): caps regs at 256/wave (prevents AGPR demotion of
// the weight arrays -- round-1 failure mode: VGPR_Count=132 + ~240
// v_accvgpr_read per step) and gives 2 waves/SIMD so independent rows hide
// each other's gate-chain latency.

#define T_ 512
#define F_ 16
#define H_ 64

__device__ __forceinline__ float fast_rcp(float a) {
    return __builtin_amdgcn_rcpf(a);   // v_rcp_f32, ~1 ULP
}
__device__ __forceinline__ float sigm(float a) {
    return fast_rcp(1.0f + __expf(-a));
}
__device__ __forceinline__ float tanh_fast(float a) {
    // tanh(a) = 1 - 2/(exp(2a)+1); saturates correctly for large |a|
    return 1.0f - 2.0f * fast_rcp(__expf(2.0f * a) + 1.0f);
}

__global__ __launch_bounds__(64, 2) void gru_fused(
    const float* __restrict__ x, const float* __restrict__ W,
    const float* __restrict__ U, const float* __restrict__ b,
    const float* __restrict__ w1, const float* __restrict__ b1,
    const float* __restrict__ gamma_, const float* __restrict__ beta_,
    const float* __restrict__ mmean, const float* __restrict__ mvar,
    const float* __restrict__ w2, const float* __restrict__ b2,
    float* __restrict__ out)
{
    const int j   = threadIdx.x;             // hidden unit, 0..63
    const int row = blockIdx.x;

    // ---- full U column triple for this lane's hidden unit (192 VGPRs) ----
    float uz[64], ur[64], uh[64];
    #pragma unroll
    for (int k = 0; k < 64; ++k) {
        uz[k] = U[k * 192 + j];
        ur[k] = U[k * 192 + 64 + j];
        uh[k] = U[k * 192 + 128 + j];
    }
    // ---- full W fragment (48 VGPRs) ----
    float wz[16], wr[16], wh[16];
    #pragma unroll
    for (int f = 0; f < 16; ++f) {
        wz[f] = W[f * 192 + j];
        wr[f] = W[f * 192 + 64 + j];
        wh[f] = W[f * 192 + 128 + j];
    }
    // biases (b is [2,192]: b[0]=input bias, b[1]=recurrent bias)
    const float bz  = b[j]       + b[192 + j];   // bi_z + br_z
    const float brr = b[64 + j]  + b[256 + j];   // bi_r + br_r
    const float bxh = b[128 + j];                // bi_h (x-part)
    const float brh = b[320 + j];                // br_h (rec-part)

    // wave-uniform x row pointer -> scalar loads
    const float4* __restrict__ xr4 =
        (const float4*)(x + (size_t)row * (T_ * F_));

    float h = 0.0f;
    for (int t = 0; t < T_; ++t) {
        // uniform address -> s_load_dwordx4 into SGPRs; consumed only after
        // the 256-instruction k-loop, so SMEM latency is hidden.
        const float4 xa = xr4[t * 4 + 0];
        const float4 xb = xr4[t * 4 + 1];
        const float4 xc = xr4[t * 4 + 2];
        const float4 xd = xr4[t * 4 + 3];

        float az = bz, ar = brr, axh = bxh, arh = brh;

        // recurrence: h[k] broadcast via readlane (SGPR operand of the FMA)
        const int hb = __float_as_int(h);
        #pragma unroll
        for (int k = 0; k < 64; ++k) {
            const float hk = __int_as_float(__builtin_amdgcn_readlane(hb, k));
            az  = fmaf(hk, uz[k], az);
            ar  = fmaf(hk, ur[k], ar);
            arh = fmaf(hk, uh[k], arh);
        }

        // input projection: x values are SGPRs (one scalar operand per FMA)
        az  = fmaf(xa.x, wz[0],  az);  ar  = fmaf(xa.x, wr[0],  ar);  axh = fmaf(xa.x, wh[0],  axh);
        az  = fmaf(xa.y, wz[1],  az);  ar  = fmaf(xa.y, wr[1],  ar);  axh = fmaf(xa.y, wh[1],  axh);
        az  = fmaf(xa.z, wz[2],  az);  ar  = fmaf(xa.z, wr[2],  ar);  axh = fmaf(xa.z, wh[2],  axh);
        az  = fmaf(xa.w, wz[3],  az);  ar  = fmaf(xa.w, wr[3],  ar);  axh = fmaf(xa.w, wh[3],  axh);
        az  = fmaf(xb.x, wz[4],  az);  ar  = fmaf(xb.x, wr[4],  ar);  axh = fmaf(xb.x, wh[4],  axh);
        az  = fmaf(xb.y, wz[5],  az);  ar  = fmaf(xb.y, wr[5],  ar);  axh = fmaf(xb.y, wh[5],  axh);
        az  = fmaf(xb.z, wz[6],  az);  ar  = fmaf(xb.z, wr[6],  ar);  axh = fmaf(xb.z, wh[6],  axh);
        az  = fmaf(xb.w, wz[7],  az);  ar  = fmaf(xb.w, wr[7],  ar);  axh = fmaf(xb.w, wh[7],  axh);
        az  = fmaf(xc.x, wz[8],  az);  ar  = fmaf(xc.x, wr[8],  ar);  axh = fmaf(xc.x, wh[8],  axh);
        az  = fmaf(xc.y, wz[9],  az);  ar  = fmaf(xc.y, wr[9],  ar);  axh = fmaf(xc.y, wh[9],  axh);
        az  = fmaf(xc.z, wz[10], az);  ar  = fmaf(xc.z, wr[10], ar);  axh = fmaf(xc.z, wh[10], axh);
        az  = fmaf(xc.w, wz[11], az);  ar  = fmaf(xc.w, wr[11], ar);  axh = fmaf(xc.w, wh[11], axh);
        az  = fmaf(xd.x, wz[12], az);  ar  = fmaf(xd.x, wr[12], ar);  axh = fmaf(xd.x, wh[12], axh);
        az  = fmaf(xd.y, wz[13], az);  ar  = fmaf(xd.y, wr[13], ar);  axh = fmaf(xd.y, wh[13], axh);
        az  = fmaf(xd.z, wz[14], az);  ar  = fmaf(xd.z, wr[14], ar);  axh = fmaf(xd.z, wh[14], axh);
        az  = fmaf(xd.w, wz[15], az);  ar  = fmaf(xd.w, wr[15], ar);  axh = fmaf(xd.w, wh[15], axh);

        // gates
        const float z  = sigm(az);
        const float r  = sigm(ar);
        const float hh = tanh_fast(fmaf(r, arh, axh));
        h = fmaf(z, h - hh, hh);
    }

    // ---- head: y = relu(h @ w1 + b1); BN(inference); out = y @ w2 + b2 ----
    float y = b1[j];
    const int hb2 = __float_as_int(h);
    #pragma unroll
    for (int k = 0; k < H_; ++k) {
        const float hk = __int_as_float(__builtin_amdgcn_readlane(hb2, k));
        y = fmaf(hk, w1[k * H_ + j], y);
    }
    y = fmaxf(y, 0.0f);
    y = fmaf((y - mmean[j]) * rsqrtf(mvar[j] + 1e-3f), gamma_[j], beta_[j]);

    float acc = y * w2[j];
    #pragma unroll
    for (int off = 32; off > 0; off >>= 1)
        acc += __shfl_down(acc, off, 64);
    if (j == 0) out[row] = acc + b2[0];
}

extern "C" void kernel_launch(void* const* d_in, const int* in_sizes, int n_in,
                              void* d_out, int out_size, void* d_ws, size_t ws_size,
                              hipStream_t stream) {
    const float* x      = (const float*)d_in[0];
    const float* W      = (const float*)d_in[1];
    const float* U      = (const float*)d_in[2];
    const float* b      = (const float*)d_in[3];
    const float* w1     = (const float*)d_in[4];
    const float* b1     = (const float*)d_in[5];
    const float* gamma_ = (const float*)d_in[6];
    const float* beta_  = (const float*)d_in[7];
    const float* mmean  = (const float*)d_in[8];
    const float* mvar   = (const float*)d_in[9];
    const float* w2     = (const float*)d_in[10];
    const float* b2     = (const float*)d_in[11];
    float* out = (float*)d_out;

    const int B = in_sizes[0] / (T_ * F_);   // 1024
    gru_fused<<<B, 64, 0, stream>>>(x, W, U, b, w1, b1, gamma_, beta_,
                                    mmean, mvar, w2, b2, out);
}

// Round 3
// 468.091 us; speedup vs baseline: 1.3159x; 1.3159x over previous
//
#include <hip/hip_runtime.h>
#include <hip/hip_fp16.h>

// GRU (reset_after, inference) fused with dense head.
// B=1024 rows, T=512 steps, F=16 features, H=64 hidden.
// ONE WAVE PER ROW: lane j owns hidden unit j.
// KEY CHANGE (round 3): weights held as packed fp16 (__half2) -> 120 VGPRs
// instead of 240 fp32. All previous rounds showed VGPR_Count ~128-132: the
// allocator parked half the fp32 weight set in AGPRs and paid a
// v_accvgpr_read per use (~2.3x VALU bloat, VALUBusy 47-72% of a 1437+ cy
// step vs ~640 cy of real work). With 120 weight regs + ~25 live scalars the
// whole state fits in arch VGPRs. Inner product uses fmaf(h, (float)h16, acc)
// which the backend folds to v_fma_mix_f32 (fp16 src via op_sel, fp32
// accumulate) -- full fp32 accumulation, half the weight registers.
// x row staged in LDS (round-1 best memory path: 16.7 MB fetch, broadcast
// ds_read_b128); h[k] broadcast via v_readlane. No barriers in the loop.

#define T_ 512
#define F_ 16
#define H_ 64

__device__ __forceinline__ float fast_rcp(float a) {
    return __builtin_amdgcn_rcpf(a);   // v_rcp_f32, ~1 ULP
}
__device__ __forceinline__ float sigm(float a) {
    return fast_rcp(1.0f + __expf(-a));
}
__device__ __forceinline__ float tanh_fast(float a) {
    // tanh(a) = 1 - 2/(exp(2a)+1); saturates correctly for large |a|
    return 1.0f - 2.0f * fast_rcp(__expf(2.0f * a) + 1.0f);
}

__global__ __launch_bounds__(64, 1) void gru_fused(
    const float* __restrict__ x, const float* __restrict__ W,
    const float* __restrict__ U, const float* __restrict__ b,
    const float* __restrict__ w1, const float* __restrict__ b1,
    const float* __restrict__ gamma_, const float* __restrict__ beta_,
    const float* __restrict__ mmean, const float* __restrict__ mvar,
    const float* __restrict__ w2, const float* __restrict__ b2,
    float* __restrict__ out)
{
    __shared__ float xs[T_ * F_];            // 32 KB: whole x row

    const int j   = threadIdx.x;             // hidden unit, 0..63
    const int row = blockIdx.x;

    // ---- stage x[row] into LDS (coalesced float4, 32 iters) ----
    const float4* xr4 = (const float4*)(x + (size_t)row * (T_ * F_));
    float4* xs4 = (float4*)xs;
    #pragma unroll
    for (int i = 0; i < (T_ * F_ / 4) / 64; ++i)   // 32 iters
        xs4[i * 64 + j] = xr4[i * 64 + j];

    // ---- weights, packed fp16 (120 VGPRs total) ----
    // uzr[k] = (uz[k], ur[k]);  uh2[m] = (uh[2m], uh[2m+1])
    __half2 uzr[64], uh2[32];
    #pragma unroll
    for (int k = 0; k < 64; ++k)
        uzr[k] = __floats2half2_rn(U[k * 192 + j], U[k * 192 + 64 + j]);
    #pragma unroll
    for (int m = 0; m < 32; ++m)
        uh2[m] = __floats2half2_rn(U[(2 * m) * 192 + 128 + j],
                                   U[(2 * m + 1) * 192 + 128 + j]);
    __half2 wzr[16], wh2[8];
    #pragma unroll
    for (int f = 0; f < 16; ++f)
        wzr[f] = __floats2half2_rn(W[f * 192 + j], W[f * 192 + 64 + j]);
    #pragma unroll
    for (int m = 0; m < 8; ++m)
        wh2[m] = __floats2half2_rn(W[(2 * m) * 192 + 128 + j],
                                   W[(2 * m + 1) * 192 + 128 + j]);

    // biases (b is [2,192]: b[0]=input bias, b[1]=recurrent bias)
    const float bz  = b[j]       + b[192 + j];   // bi_z + br_z
    const float brr = b[64 + j]  + b[256 + j];   // bi_r + br_r
    const float bxh = b[128 + j];                // bi_h (x-part)
    const float brh = b[320 + j];                // br_h (rec-part)

    __syncthreads();   // xs ready

    float h = 0.0f;
    for (int t = 0; t < T_; ++t) {
        // uniform-address LDS reads -> broadcast, no conflicts; consumed
        // after the k-loop so ds latency hides under ~256 FMAs.
        const float4 xa = xs4[t * 4 + 0];
        const float4 xb = xs4[t * 4 + 1];
        const float4 xc = xs4[t * 4 + 2];
        const float4 xd = xs4[t * 4 + 3];

        float az = bz, ar = brr, axh = bxh, arh = brh;

        // recurrence: h[k] broadcast via readlane; weights fp16 via fma_mix
        const int hb = __float_as_int(h);
        #pragma unroll
        for (int m = 0; m < 32; ++m) {
            const float h0 = __int_as_float(__builtin_amdgcn_readlane(hb, 2 * m));
            const float h1 = __int_as_float(__builtin_amdgcn_readlane(hb, 2 * m + 1));
            az  = fmaf(h0, __low2float (uzr[2 * m]),     az);
            ar  = fmaf(h0, __high2float(uzr[2 * m]),     ar);
            arh = fmaf(h0, __low2float (uh2[m]),         arh);
            az  = fmaf(h1, __low2float (uzr[2 * m + 1]), az);
            ar  = fmaf(h1, __high2float(uzr[2 * m + 1]), ar);
            arh = fmaf(h1, __high2float(uh2[m]),         arh);
        }

        // input projection
        float xf[16];
        *(float4*)&xf[0]  = xa;
        *(float4*)&xf[4]  = xb;
        *(float4*)&xf[8]  = xc;
        *(float4*)&xf[12] = xd;
        #pragma unroll
        for (int f = 0; f < 16; ++f) {
            az  = fmaf(xf[f], __low2float (wzr[f]), az);
            ar  = fmaf(xf[f], __high2float(wzr[f]), ar);
            axh = fmaf(xf[f], (f & 1) ? __high2float(wh2[f >> 1])
                                      : __low2float (wh2[f >> 1]), axh);
        }

        // gates
        const float z  = sigm(az);
        const float r  = sigm(ar);
        const float hh = tanh_fast(fmaf(r, arh, axh));
        h = fmaf(z, h - hh, hh);
    }

    // ---- head: y = relu(h @ w1 + b1); BN(inference); out = y @ w2 + b2 ----
    // once per row; fp32 weights from global (cache-hot), negligible cost
    float y = b1[j];
    const int hb2 = __float_as_int(h);
    #pragma unroll
    for (int k = 0; k < H_; ++k) {
        const float hk = __int_as_float(__builtin_amdgcn_readlane(hb2, k));
        y = fmaf(hk, w1[k * H_ + j], y);
    }
    y = fmaxf(y, 0.0f);
    y = fmaf((y - mmean[j]) * rsqrtf(mvar[j] + 1e-3f), gamma_[j], beta_[j]);

    float acc = y * w2[j];
    #pragma unroll
    for (int off = 32; off > 0; off >>= 1)
        acc += __shfl_down(acc, off, 64);
    if (j == 0) out[row] = acc + b2[0];
}

extern "C" void kernel_launch(void* const* d_in, const int* in_sizes, int n_in,
                              void* d_out, int out_size, void* d_ws, size_t ws_size,
                              hipStream_t stream) {
    const float* x      = (const float*)d_in[0];
    const float* W      = (const float*)d_in[1];
    const float* U      = (const float*)d_in[2];
    const float* b      = (const float*)d_in[3];
    const float* w1     = (const float*)d_in[4];
    const float* b1     = (const float*)d_in[5];
    const float* gamma_ = (const float*)d_in[6];
    const float* beta_  = (const float*)d_in[7];
    const float* mmean  = (const float*)d_in[8];
    const float* mvar   = (const float*)d_in[9];
    const float* w2     = (const float*)d_in[10];
    const float* b2     = (const float*)d_in[11];
    float* out = (float*)d_out;

    const int B = in_sizes[0] / (T_ * F_);   // 1024
    gru_fused<<<B, 64, 0, stream>>>(x, W, U, b, w1, b1, gamma_, beta_,
                                    mmean, mvar, w2, b2, out);
}

// Round 4
// 264.681 us; speedup vs baseline: 2.3273x; 1.7685x over previous
//
#include <hip/hip_runtime.h>
#include <hip/hip_fp16.h>

// GRU (reset_after, inference) fused with dense head.
// B=1024 rows, T=512 steps, F=16 features, H=64 hidden. ONE WAVE PER ROW.
// Round-4 structure: v_dot2_f32_f16 everywhere.
//   - Weights packed along k as half2: 120 VGPRs, no AGPR demotion.
//   - Inner product = 120 x v_dot2_f32_f16 (2 MAC/instr, fp32 accumulate).
//     Round 3 showed fma_mix folding does NOT fire (690 instr/step measured
//     vs 330 source): dot2 needs no folding heuristics and no v_cvt.
//   - h broadcast WITHOUT readlane: lane j writes (half)h to a 128-B LDS
//     buffer (ds_write_b16); all lanes read it back with uniform addresses
//     (8 x ds_read_b128 broadcast, conflict-free). Removes 64 v_readlane +
//     SGPR hazard stalls per step.
//   - x staged once as packed fp16 in LDS (16 KB), 2 uniform ds_read_b128
//     per step.
// Per-step issue: ~150 instr (~300 cy) vs ~690 before.

#define T_ 512
#define F_ 16
#define H_ 64

typedef _Float16 half_t;
typedef _Float16 h2 __attribute__((ext_vector_type(2)));
typedef _Float16 h4 __attribute__((ext_vector_type(4)));
typedef _Float16 h8 __attribute__((ext_vector_type(8)));

__device__ __forceinline__ float fdot2f(h2 a, h2 b, float c) {
#if __has_builtin(__builtin_amdgcn_fdot2)
    return __builtin_amdgcn_fdot2(a, b, c, false);   // v_dot2_f32_f16
#else
    return fmaf((float)a.x, (float)b.x, fmaf((float)a.y, (float)b.y, c));
#endif
}

__device__ __forceinline__ float fast_rcp(float a) {
    return __builtin_amdgcn_rcpf(a);   // v_rcp_f32, ~1 ULP
}
__device__ __forceinline__ float sigm(float a) {
    return fast_rcp(1.0f + __expf(-a));
}
__device__ __forceinline__ float tanh_fast(float a) {
    // tanh(a) = 1 - 2/(exp(2a)+1); saturates correctly for large |a|
    return 1.0f - 2.0f * fast_rcp(__expf(2.0f * a) + 1.0f);
}

__global__ __launch_bounds__(64, 1) void gru_fused(
    const float* __restrict__ x, const float* __restrict__ W,
    const float* __restrict__ U, const float* __restrict__ b,
    const float* __restrict__ w1, const float* __restrict__ b1,
    const float* __restrict__ gamma_, const float* __restrict__ beta_,
    const float* __restrict__ mmean, const float* __restrict__ mvar,
    const float* __restrict__ w2, const float* __restrict__ b2,
    float* __restrict__ out)
{
    __shared__ __align__(16) half_t xs16[T_ * F_];   // 16 KB: x row, fp16
    __shared__ __align__(16) half_t hb16[H_];        // 128 B: h broadcast

    const int j   = threadIdx.x;             // hidden unit, 0..63
    const int row = blockIdx.x;

    // ---- stage x[row] into LDS as packed fp16 (32 iters) ----
    const float4* xr4 = (const float4*)(x + (size_t)row * (T_ * F_));
    #pragma unroll
    for (int i = 0; i < (T_ * F_ / 4) / 64; ++i) {   // 32 iters
        const float4 v = xr4[i * 64 + j];
        h4 p = { (half_t)v.x, (half_t)v.y, (half_t)v.z, (half_t)v.w };
        ((h4*)xs16)[i * 64 + j] = p;                 // ds_write_b64
    }
    hb16[j] = (half_t)0.0f;                          // h0 = 0

    // ---- weights packed along k as half2 (120 VGPRs) ----
    h2 uz2[32], ur2[32], uh2[32];
    #pragma unroll
    for (int m = 0; m < 32; ++m) {
        uz2[m] = h2{ (half_t)U[(2*m)*192 +       j], (half_t)U[(2*m+1)*192 +       j] };
        ur2[m] = h2{ (half_t)U[(2*m)*192 +  64 + j], (half_t)U[(2*m+1)*192 +  64 + j] };
        uh2[m] = h2{ (half_t)U[(2*m)*192 + 128 + j], (half_t)U[(2*m+1)*192 + 128 + j] };
    }
    h2 wz2[8], wr2[8], wh2[8];
    #pragma unroll
    for (int p = 0; p < 8; ++p) {
        wz2[p] = h2{ (half_t)W[(2*p)*192 +       j], (half_t)W[(2*p+1)*192 +       j] };
        wr2[p] = h2{ (half_t)W[(2*p)*192 +  64 + j], (half_t)W[(2*p+1)*192 +  64 + j] };
        wh2[p] = h2{ (half_t)W[(2*p)*192 + 128 + j], (half_t)W[(2*p+1)*192 + 128 + j] };
    }
    // biases (b is [2,192]: b[0]=input bias, b[1]=recurrent bias)
    const float bz  = b[j]       + b[192 + j];   // bi_z + br_z
    const float brr = b[64 + j]  + b[256 + j];   // bi_r + br_r
    const float bxh = b[128 + j];                // bi_h (x-part)
    const float brh = b[320 + j];                // br_h (rec-part)

    __syncthreads();   // LDS visible (single wave: folds to a waitcnt)

    float h = 0.0f;
    for (int t = 0; t < T_; ++t) {
        // uniform-address LDS reads -> broadcast, conflict-free.
        // x first (no dependence), then h (written at end of prev step;
        // DS pipeline is in-order per wave, so no barrier needed).
        h2 xp[8];
        #pragma unroll
        for (int q = 0; q < 2; ++q)
            *((h8*)&xp[4 * q]) = ((const h8*)xs16)[t * 2 + q];  // ds_read_b128
        h2 hp[32];
        #pragma unroll
        for (int q = 0; q < 8; ++q)
            *((h8*)&hp[4 * q]) = ((const h8*)hb16)[q];          // ds_read_b128

        float az = bz, ar = brr, axh = bxh, arh = brh;

        // input projection: 24 dot2 (consumes xp while hp still in flight)
        #pragma unroll
        for (int p = 0; p < 8; ++p) {
            az  = fdot2f(xp[p], wz2[p], az);
            ar  = fdot2f(xp[p], wr2[p], ar);
            axh = fdot2f(xp[p], wh2[p], axh);
        }
        // recurrence: 96 dot2
        #pragma unroll
        for (int m = 0; m < 32; ++m) {
            az  = fdot2f(hp[m], uz2[m], az);
            ar  = fdot2f(hp[m], ur2[m], ar);
            arh = fdot2f(hp[m], uh2[m], arh);
        }

        // gates
        const float z  = sigm(az);
        const float r  = sigm(ar);
        const float hh = tanh_fast(fmaf(r, arh, axh));
        h = fmaf(z, h - hh, hh);

        // publish h for next step (fp32 state stays in register)
        hb16[j] = (half_t)h;                                    // ds_write_b16
    }

    // ---- head: y = relu(h @ w1 + b1); BN(inference); out = y @ w2 + b2 ----
    float y = b1[j];
    const int hb2 = __float_as_int(h);
    #pragma unroll
    for (int k = 0; k < H_; ++k) {
        const float hk = __int_as_float(__builtin_amdgcn_readlane(hb2, k));
        y = fmaf(hk, w1[k * H_ + j], y);
    }
    y = fmaxf(y, 0.0f);
    y = fmaf((y - mmean[j]) * rsqrtf(mvar[j] + 1e-3f), gamma_[j], beta_[j]);

    float acc = y * w2[j];
    #pragma unroll
    for (int off = 32; off > 0; off >>= 1)
        acc += __shfl_down(acc, off, 64);
    if (j == 0) out[row] = acc + b2[0];
}

extern "C" void kernel_launch(void* const* d_in, const int* in_sizes, int n_in,
                              void* d_out, int out_size, void* d_ws, size_t ws_size,
                              hipStream_t stream) {
    const float* x      = (const float*)d_in[0];
    const float* W      = (const float*)d_in[1];
    const float* U      = (const float*)d_in[2];
    const float* b      = (const float*)d_in[3];
    const float* w1     = (const float*)d_in[4];
    const float* b1     = (const float*)d_in[5];
    const float* gamma_ = (const float*)d_in[6];
    const float* beta_  = (const float*)d_in[7];
    const float* mmean  = (const float*)d_in[8];
    const float* mvar   = (const float*)d_in[9];
    const float* w2     = (const float*)d_in[10];
    const float* b2     = (const float*)d_in[11];
    float* out = (float*)d_out;

    const int B = in_sizes[0] / (T_ * F_);   // 1024
    gru_fused<<<B, 64, 0, stream>>>(x, W, U, b, w1, b1, gamma_, beta_,
                                    mmean, mvar, w2, b2, out);
}